// Round 2
// 1167.270 us; speedup vs baseline: 1.1349x; 1.1349x over previous
//
#include <hip/hip_runtime.h>
#include <hip/hip_bf16.h>

// Flash-attention fwd with additive bias, fp32 in/out, bf16 MFMA compute.
// B=4 S=2048 H=12 D=64; bias [b,h,sq,sk] is 805 MB -> HBM-bound on bias stream.
// R2: software-pipelined K-tile loop (reg-prefetch K/V/bias one tile ahead,
// bias folded into MFMA C-init, XCD-chunk swizzle, nontemporal bias) but with
// plain __syncthreads() barriers — isolating the pipeline win from the raw
// s_barrier discipline that may have wedged R1. Prefetch is issued at the top
// of compute and first needed at the next iteration's barrier, so the
// vmcnt(0) drain inside __syncthreads costs only the un-hidden tail.
#define B_ 4
#define S_ 2048
#define H_ 12
#define D_ 64
#define QT 64
#define KT 64
#define NQT (S_/QT)   // 32
#define NKT (S_/KT)   // 32
#define NXCD 8
#define LOG2E 1.44269504088896340736f

typedef __bf16 bf16x8 __attribute__((ext_vector_type(8)));
typedef __bf16 bf16x4 __attribute__((ext_vector_type(4)));
typedef float  f32x4  __attribute__((ext_vector_type(4)));

// MFMA 16x16x32 bf16 layouts (learn_hip m89/m91/m120 verified):
//   A[m=lane&15][k=(lane>>4)*8+j]   B[k=(lane>>4)*8+j][n=lane&15]
//   C/D: col=lane&15, row=(lane>>4)*4+reg
__global__ __launch_bounds__(256, 4) void fa_fwd(
    const float* __restrict__ Q, const float* __restrict__ K,
    const float* __restrict__ V, const float* __restrict__ Bias,
    float* __restrict__ Out)
{
  // stride 72 (bf16): 144 B rows -> 16B-aligned b128 frag reads, 2-way banks.
  // Vt stride 68: 136 B rows -> 8B-aligned b64 pair reads, ~4-way banks.
  __shared__ __attribute__((aligned(16))) __bf16 Qs[QT*72];
  __shared__ __attribute__((aligned(16))) __bf16 Ks[KT*72];
  __shared__ __attribute__((aligned(16))) __bf16 Vt[D_*68];
  __shared__ __attribute__((aligned(16))) __bf16 Ps[4*16*72];

  // XCD-chunk swizzle (bijective: 1536 % 8 == 0). HW round-robins blockIdx
  // over 8 XCDs; remap so each XCD owns contiguous logical ids -> the 32
  // q-tiles of one (b,h) share that XCD's L2 for K/V.
  const int nper = (B_*H_*NQT)/NXCD;          // 192
  const int bid  = (blockIdx.x % NXCD)*nper + (blockIdx.x / NXCD);
  const int qt  = bid & (NQT-1);
  const int bh  = bid >> 5;          // log2(NQT)
  const int b   = bh / H_;
  const int h   = bh - b*H_;
  const int q0  = qt*QT;

  const int tid  = threadIdx.x;
  const int w    = tid >> 6;         // wave 0..3 -> q rows 16w..16w+15
  const int lane = tid & 63;
  const int g    = lane >> 4;        // quad
  const int c    = lane & 15;

  const int sr0 = tid >> 4;          // staging row base (0..15), +16*i
  const int d4  = (tid & 15) << 2;   // staging d offset

  const float qscale = 0.125f * LOG2E;  // fold softmax scale + base-2 into Q

  // ---- load Q tile once (pre-scaled, bf16) ----
  #pragma unroll
  for (int i = 0; i < 4; ++i) {
    const int qr = sr0 + 16*i;
    float4 qv = *(const float4*)(Q + (((size_t)b*S_ + q0 + qr)*H_ + h)*D_ + d4);
    bf16x4 pk;
    pk[0] = (__bf16)(qv.x * qscale); pk[1] = (__bf16)(qv.y * qscale);
    pk[2] = (__bf16)(qv.z * qscale); pk[3] = (__bf16)(qv.w * qscale);
    *(bf16x4*)&Qs[qr*72 + d4] = pk;
  }

  f32x4 Ov[4] = {};                 // O accumulator, C-layout, 4 d-subtiles
  float m_i[4], l_i[4];
  #pragma unroll
  for (int r = 0; r < 4; ++r) { m_i[r] = -1e30f; l_i[r] = 0.f; }

  const size_t row_base = (size_t)q0 + 16*w + 4*g;
  const float* bb    = Bias + ((size_t)bh*S_ + row_base)*S_ + c;
  const float* kbase = K + ((size_t)b*S_*H_ + h)*D_ + (size_t)sr0*H_*D_ + d4;
  const float* vbase = V + ((size_t)b*S_*H_ + h)*D_ + (size_t)sr0*H_*D_ + d4;

  // ---- prologue: prefetch tile 0 into regs ----
  float4 kreg[4], vreg[4];
  #pragma unroll
  for (int i = 0; i < 4; ++i) {
    kreg[i] = *(const float4*)(kbase + (size_t)16*i*H_*D_);
    vreg[i] = *(const float4*)(vbase + (size_t)16*i*H_*D_);
  }
  // bias tile 0 (C-layout: bl[t][r] = Bias[q=4g+r(+16w+q0)][k=16t+c]).
  // nontemporal: bias is a single-use 805MB stream -> don't pollute L2.
  float bl[4][4];
  #pragma unroll
  for (int t = 0; t < 4; ++t)
    #pragma unroll
    for (int r = 0; r < 4; ++r)
      bl[t][r] = __builtin_nontemporal_load(bb + (size_t)r*S_ + 16*t);

  for (int kt = 0; kt < NKT; ++kt) {
    // A: all waves done reading tile kt-1 fragments before we overwrite.
    __syncthreads();

    // ---- commit staged K/V regs (tile kt) to LDS ----
    // (loads were issued a full compute-phase ago -> latency mostly hidden)
    #pragma unroll
    for (int i = 0; i < 4; ++i) {
      const int kr = sr0 + 16*i;
      float4 kv = kreg[i];
      bf16x4 pk;
      pk[0]=(__bf16)kv.x; pk[1]=(__bf16)kv.y; pk[2]=(__bf16)kv.z; pk[3]=(__bf16)kv.w;
      *(bf16x4*)&Ks[kr*72 + d4] = pk;
      float4 vv = vreg[i];
      Vt[(d4+0)*68 + kr] = (__bf16)vv.x;
      Vt[(d4+1)*68 + kr] = (__bf16)vv.y;
      Vt[(d4+2)*68 + kr] = (__bf16)vv.z;
      Vt[(d4+3)*68 + kr] = (__bf16)vv.w;
    }

    // B: tile kt visible to all waves.
    __syncthreads();

    // ---- issue K/V prefetch for tile kt+1 (hidden under this compute) ----
    if (kt + 1 < NKT) {
      const float* kp = kbase + (size_t)(kt+1)*KT*H_*D_;
      const float* vp = vbase + (size_t)(kt+1)*KT*H_*D_;
      #pragma unroll
      for (int i = 0; i < 4; ++i) {
        kreg[i] = *(const float4*)(kp + (size_t)16*i*H_*D_);
        vreg[i] = *(const float4*)(vp + (size_t)16*i*H_*D_);
      }
    }

    // ---- S = Q*K^T (scaled,base2) + bias*log2e (bias as MFMA C-init) ----
    bf16x8 aq0 = *(const bf16x8*)&Qs[(16*w + c)*72 + 8*g];
    bf16x8 aq1 = *(const bf16x8*)&Qs[(16*w + c)*72 + 32 + 8*g];
    float sc[4][4];
    #pragma unroll
    for (int t = 0; t < 4; ++t) {
      bf16x8 bk0 = *(const bf16x8*)&Ks[(16*t + c)*72 + 8*g];
      bf16x8 bk1 = *(const bf16x8*)&Ks[(16*t + c)*72 + 32 + 8*g];
      f32x4 acc;
      acc[0] = bl[t][0]*LOG2E; acc[1] = bl[t][1]*LOG2E;
      acc[2] = bl[t][2]*LOG2E; acc[3] = bl[t][3]*LOG2E;
      acc = __builtin_amdgcn_mfma_f32_16x16x32_bf16(aq0, bk0, acc, 0, 0, 0);
      acc = __builtin_amdgcn_mfma_f32_16x16x32_bf16(aq1, bk1, acc, 0, 0, 0);
      #pragma unroll
      for (int r = 0; r < 4; ++r)
        sc[t][r] = acc[r];
    }

    // bias regs consumed -> issue bias prefetch for tile kt+1 now; its
    // latency hides under softmax+PV of this iteration.
    if (kt + 1 < NKT) {
      const float* bp = bb + (size_t)(kt+1)*KT;
      #pragma unroll
      for (int t = 0; t < 4; ++t)
        #pragma unroll
        for (int r = 0; r < 4; ++r)
          bl[t][r] = __builtin_nontemporal_load(bp + (size_t)r*S_ + 16*t);
    }

    // ---- online softmax (rows 4g+r; reduce over cols = 16-lane group) ----
    #pragma unroll
    for (int r = 0; r < 4; ++r) {
      float mv = fmaxf(fmaxf(sc[0][r], sc[1][r]), fmaxf(sc[2][r], sc[3][r]));
      #pragma unroll
      for (int mask = 1; mask <= 8; mask <<= 1)
        mv = fmaxf(mv, __shfl_xor(mv, mask, 64));
      float mn = fmaxf(m_i[r], mv);
      float alpha = __builtin_amdgcn_exp2f(m_i[r] - mn);
      m_i[r] = mn;
      float rs = 0.f;
      #pragma unroll
      for (int t = 0; t < 4; ++t) {
        float p = __builtin_amdgcn_exp2f(sc[t][r] - mn);
        sc[t][r] = p;
        rs += p;
      }
      #pragma unroll
      for (int mask = 1; mask <= 8; mask <<= 1)
        rs += __shfl_xor(rs, mask, 64);
      l_i[r] = l_i[r]*alpha + rs;
      #pragma unroll
      for (int t = 0; t < 4; ++t)
        Ov[t][r] *= alpha;
    }

    // ---- P: C-layout -> A-layout via per-wave-private LDS ----
    #pragma unroll
    for (int t = 0; t < 4; ++t)
      #pragma unroll
      for (int r = 0; r < 4; ++r)
        Ps[w*1152 + (4*g + r)*72 + 16*t + c] = (__bf16)sc[t][r];
    // (same-wave LDS RAW: compiler inserts lgkmcnt; no block barrier needed)

    // ---- O += P*V ----
    #pragma unroll
    for (int hh = 0; hh < 2; ++hh) {
      bf16x8 ap = *(const bf16x8*)&Ps[w*1152 + c*72 + 32*hh + 8*g];
      #pragma unroll
      for (int t = 0; t < 4; ++t) {
        union { bf16x8 v8; bf16x4 v4[2]; } bv;
        bv.v4[0] = *(const bf16x4*)&Vt[(16*t + c)*68 + 32*hh + 8*g];
        bv.v4[1] = *(const bf16x4*)&Vt[(16*t + c)*68 + 32*hh + 8*g + 4];
        Ov[t] = __builtin_amdgcn_mfma_f32_16x16x32_bf16(ap, bv.v8, Ov[t], 0, 0, 0);
      }
    }
  }

  // ---- epilogue: O / l, write [b, q, h, d] fp32 ----
  float* ob = Out + (((size_t)b*S_ + row_base)*H_ + h)*D_ + c;
  #pragma unroll
  for (int r = 0; r < 4; ++r) {
    float inv = 1.0f / l_i[r];
    #pragma unroll
    for (int t = 0; t < 4; ++t)
      ob[(size_t)r*H_*D_ + 16*t] = Ov[t][r] * inv;
  }
}

extern "C" void kernel_launch(void* const* d_in, const int* in_sizes, int n_in,
                              void* d_out, int out_size, void* d_ws, size_t ws_size,
                              hipStream_t stream) {
  const float* q    = (const float*)d_in[0];
  const float* k    = (const float*)d_in[1];
  const float* v    = (const float*)d_in[2];
  const float* bias = (const float*)d_in[3];
  float* out = (float*)d_out;
  dim3 grid(B_ * H_ * NQT);   // 1536 blocks
  fa_fwd<<<grid, 256, 0, stream>>>(q, k, v, bias, out);
}